// Round 12
// baseline (376.254 us; speedup 1.0000x reference)
//
#include <hip/hip_runtime.h>

#define NTOK 4096
#define KK   3276   // int(4096 * 0.8)
#define LOG2E 1.4426950408889634f
#define TC1 0.69314718056f     // ln2
#define TC2 0.24022650696f     // ln2^2/2

typedef float f32x8 __attribute__((ext_vector_type(8)));

#define ROWS(M) M(0) M(1) M(2) M(3)

__device__ __forceinline__ unsigned key_of(float f) {
    unsigned u = __float_as_uint(f);
    return (u & 0x80000000u) ? ~u : (u | 0x80000000u);
}
__device__ __forceinline__ float float_of_key(unsigned k) {
    unsigned u = (k & 0x80000000u) ? (k ^ 0x80000000u) : ~k;
    return __uint_as_float(u);
}
__device__ __forceinline__ float rflf(float x) {
    return __int_as_float(__builtin_amdgcn_readfirstlane(__float_as_int(x)));
}
__device__ __forceinline__ unsigned rflu(unsigned x) {
    return (unsigned)__builtin_amdgcn_readfirstlane((int)x);
}
__device__ __forceinline__ unsigned idx_of(float s, float C, float B) {
    unsigned i = (unsigned)(fmaf(s, C, B));   // v_cvt_u32_f32 clamps <0 -> 0
    return i > 1023u ? 1023u : i;
}

// one wave scans a 1024-bin histogram: find largest bin `dig` such that
// suffix-count(dig) >= need; write {dig, need - suffix(dig+1), count(dig)}.
__device__ __forceinline__ void scan1024(const unsigned* __restrict__ h, int lane,
                                         unsigned need, unsigned* __restrict__ selp) {
    const uint4* h4 = (const uint4*)(h + (lane << 4));
    uint4 u0 = h4[0], u1 = h4[1], u2 = h4[2], u3 = h4[3];
    unsigned f15 = u3.w;
    unsigned f14 = u3.z + f15, f13 = u3.y + f14, f12 = u3.x + f13;
    unsigned f11 = u2.w + f12, f10 = u2.z + f11, f9 = u2.y + f10, f8 = u2.x + f9;
    unsigned f7 = u1.w + f8, f6 = u1.z + f7, f5 = u1.y + f6, f4 = u1.x + f5;
    unsigned f3 = u0.w + f4, f2 = u0.z + f3, f1 = u0.y + f2, f0 = u0.x + f1;
    unsigned ls = f0;
    unsigned S = ls;
    #pragma unroll
    for (int off = 1; off < 64; off <<= 1) {
        unsigned v = __shfl_down(S, off, 64);
        if (lane + off < 64) S += v;
    }
    unsigned above = S - ls;       // suffix count of lanes > this lane
    if (above < need && above + ls >= need) {
        unsigned kk = 0, selCur = f0, selNext = f1;
        #define STEP(k, fk, fk1) if (above + (fk) >= need) { kk = k; selCur = (fk); selNext = (fk1); }
        STEP(0, f0, f1)  STEP(1, f1, f2)   STEP(2, f2, f3)   STEP(3, f3, f4)
        STEP(4, f4, f5)  STEP(5, f5, f6)   STEP(6, f6, f7)   STEP(7, f7, f8)
        STEP(8, f8, f9)  STEP(9, f9, f10)  STEP(10, f10, f11) STEP(11, f11, f12)
        STEP(12, f12, f13) STEP(13, f13, f14) STEP(14, f14, f15) STEP(15, f15, 0u)
        #undef STEP
        selp[0] = (unsigned)(lane << 4) + kk;
        selp[1] = need - (above + selNext);
        selp[2] = selCur - selNext;
    }
}

// Fused: pointwise-over-t conv + depthwise 3x3 + scatter to [head][n][4] + sum-of-squares
__global__ __launch_bounds__(256) void k_fused(const float* __restrict__ x,
                                               const float* __restrict__ wq,
                                               const float* __restrict__ wdw,
                                               float* __restrict__ qh,
                                               float* __restrict__ kh,
                                               float* __restrict__ vh,
                                               float* __restrict__ ss) {
    __shared__ float p[1024];
    int b = blockIdx.x;
    int o = b >> 5, c = b & 31;
    int tid = threadIdx.x;
    float w0 = wq[o * 4 + 0], w1 = wq[o * 4 + 1], w2 = wq[o * 4 + 2], w3 = wq[o * 4 + 3];
    const float* x0 = x + (c << 10);
    #pragma unroll
    for (int r = 0; r < 4; ++r) {
        int hw = tid + (r << 8);
        float a = w0 * x0[hw];
        a = fmaf(w1, x0[(32 << 10) + hw], a);
        a = fmaf(w2, x0[(64 << 10) + hw], a);
        a = fmaf(w3, x0[(96 << 10) + hw], a);
        p[hw] = a;
    }
    __syncthreads();
    float wd[9];
    #pragma unroll
    for (int i = 0; i < 9; ++i) wd[i] = wdw[o * 9 + i];
    int g = o >> 2, t = o & 3;
    int head = c >> 2, cph = c & 3;
    float* dst = (g == 0) ? qh : (g == 1) ? kh : vh;
    float ssum = 0.f;
    #pragma unroll
    for (int r = 0; r < 4; ++r) {
        int hw = tid + (r << 8);
        int wcol = hw & 31, hrow = hw >> 5;
        float a = 0.f;
        #pragma unroll
        for (int dy = -1; dy <= 1; ++dy) {
            int hh = hrow + dy;
            if (hh < 0 || hh > 31) continue;
            #pragma unroll
            for (int dx = -1; dx <= 1; ++dx) {
                int ww = wcol + dx;
                if (ww < 0 || ww > 31) continue;
                a = fmaf(wd[(dy + 1) * 3 + (dx + 1)], p[hh * 32 + ww], a);
            }
        }
        int n = (hw << 2) + t;
        dst[(((head << 12) + n) << 2) + cph] = a;
        ssum = fmaf(a, a, ssum);
    }
    if (g < 2) {
        #pragma unroll
        for (int off = 32; off > 0; off >>= 1) ssum += __shfl_down(ssum, off, 64);
        if ((tid & 63) == 0) atomicAdd(&ss[g * 32 + c], ssum);
    }
}

// One block per (head, 4 rows), 512 threads / 8 waves. Scores (log2-scaled) in
// registers (8/row/thread); 3-pass x 1024-bin fixed-point radix select; waves
// 0-3 scan the 4 rows concurrently, waves 4-7 clear the ping-pong buffer.
__global__ __launch_bounds__(512, 4) void k_attn(const float* __restrict__ qh,
                                                 const float* __restrict__ kh,
                                                 const float* __restrict__ vh,
                                                 const float* __restrict__ ss,
                                                 const float* __restrict__ temp,
                                                 float* __restrict__ outp) {
    __shared__ __align__(16) unsigned hist[2][4][1024];  // 32 KB
    __shared__ uint2 mm[8][4];
    __shared__ float4 rng[4];
    __shared__ unsigned selLds[4][3];
    __shared__ float red[8][4][5];

    int bid = blockIdx.x;
    int head = bid >> 10;
    int n0 = (bid & 1023) << 2;
    int tid = threadIdx.x;
    int lane = tid & 63;
    int wv = tid >> 6;

    // clear both histogram buffers (8192 words)
    unsigned* hb = &hist[0][0][0];
    #pragma unroll
    for (int i = 0; i < 16; ++i) hb[tid + (i << 9)] = 0;

    // per-cph combined scale: log2e * temp / (||q_c||*||k_c||), folded into q
    float tempv = temp[head] * LOG2E;
    const float* sq = ss + head * 4;
    const float* sk = ss + 32 + head * 4;
    float f0 = tempv / (fmaxf(sqrtf(sq[0]), 1e-12f) * fmaxf(sqrtf(sk[0]), 1e-12f));
    float f1 = tempv / (fmaxf(sqrtf(sq[1]), 1e-12f) * fmaxf(sqrtf(sk[1]), 1e-12f));
    float f2 = tempv / (fmaxf(sqrtf(sq[2]), 1e-12f) * fmaxf(sqrtf(sk[2]), 1e-12f));
    float f3 = tempv / (fmaxf(sqrtf(sq[3]), 1e-12f) * fmaxf(sqrtf(sk[3]), 1e-12f));

    const float4* kb4 = (const float4*)kh + (head << 12);
    const float4* vb4 = (const float4*)vh + (head << 12);
#define DECLQ(r) float4 q##r = ((const float4*)qh)[(head << 12) + n0 + r]; \
    q##r.x *= f0; q##r.y *= f1; q##r.z *= f2; q##r.w *= f3;
    ROWS(DECLQ)

    // Phase 1: scores in registers + per-row min/max
#define DECLS(r) f32x8 s##r; float mn##r = INFINITY, mx##r = -INFINITY;
    ROWS(DECLS)
    #pragma unroll
    for (int j = 0; j < 8; ++j) {
        float4 kv = kb4[tid + (j << 9)];
#define DOT(r) { float v = fmaf(q##r.w, kv.w, fmaf(q##r.z, kv.z, fmaf(q##r.y, kv.y, q##r.x * kv.x))); \
        s##r[j] = v; mn##r = fminf(mn##r, v); mx##r = fmaxf(mx##r, v); }
        ROWS(DOT)
    }
    #pragma unroll
    for (int off = 32; off > 0; off >>= 1) {
#define RED1(r) mn##r = fminf(mn##r, __shfl_down(mn##r, off, 64)); \
        mx##r = fmaxf(mx##r, __shfl_down(mx##r, off, 64));
        ROWS(RED1)
    }
    if (lane == 0) {
#define WRMM(r) mm[wv][r] = make_uint2(key_of(mn##r), key_of(mx##r));
        ROWS(WRMM)
    }
    __syncthreads();                                    // B1: clears + mm

    // wave r (<4) reduces row r's range and publishes binning constants
    if (wv < 4) {
        unsigned kmn = 0xFFFFFFFFu, kmx = 0u;
        if (lane < 8) { uint2 v = mm[lane][wv]; kmn = v.x; kmx = v.y; }
        #pragma unroll
        for (int off = 4; off > 0; off >>= 1) {
            unsigned a = (unsigned)__shfl_down((int)kmn, off, 64);
            unsigned b = (unsigned)__shfl_down((int)kmx, off, 64);
            kmn = kmn < a ? kmn : a;
            kmx = kmx > b ? kmx : b;
        }
        if (lane == 0) {
            float mnf = float_of_key(kmn), mxf = float_of_key(kmx);
            float rg = fmaxf(mxf - mnf, 1e-30f);
            float C0 = 1023.0f / rg;
            rng[wv] = make_float4(C0, -mnf * C0, mxf, rg);
        }
    }
    __syncthreads();                                    // B1b

#define RDRNG(r) float4 rv##r = rng[r]; \
    float C0_##r = rflf(rv##r.x), B0_##r = rflf(rv##r.y), MX_##r = rflf(rv##r.z);
    ROWS(RDRNG)
    float rgmax = fmaxf(fmaxf(rflf(rv0.w), rflf(rv1.w)), fmaxf(rflf(rv2.w), rflf(rv3.w)));
    bool taylor = rgmax < 0.04f;

    // pass 0 atomics (buf 0)
    #pragma unroll
    for (int j = 0; j < 8; ++j) {
#define H0(r) atomicAdd(&hist[0][r][idx_of(s##r[j], C0_##r, B0_##r)], 1u);
        ROWS(H0)
    }
    __syncthreads();                                    // B2
    if (wv < 4) scan1024(hist[0][wv], lane, KK, selLds[wv]);
    __syncthreads();                                    // B3

#define SEL0(r) unsigned d0_##r = rflu(selLds[r][0]); unsigned nn_##r = rflu(selLds[r][1]); \
    float C1_##r = 1023.0f * C0_##r, B1_##r = 1023.0f * (B0_##r - (float)d0_##r);
    ROWS(SEL0)

    // post-scan0: abv/eqc masks (bit j+8r), pass-1 atomics (buf 1)
    unsigned abv = 0, eqc = 0;
    #pragma unroll
    for (int j = 0; j < 8; ++j) {
#define PS0(r) { unsigned i0 = idx_of(s##r[j], C0_##r, B0_##r); \
        if (i0 > d0_##r) abv |= 1u << (j + 8 * r); \
        else if (i0 == d0_##r) { eqc |= 1u << (j + 8 * r); \
            atomicAdd(&hist[1][r][idx_of(s##r[j], C1_##r, B1_##r)], 1u); } }
        ROWS(PS0)
    }
    __syncthreads();                                    // B4
    if (wv == 0)      scan1024(hist[1][0], lane, nn_0, selLds[0]);
    else if (wv == 1) scan1024(hist[1][1], lane, nn_1, selLds[1]);
    else if (wv == 2) scan1024(hist[1][2], lane, nn_2, selLds[2]);
    else if (wv == 3) scan1024(hist[1][3], lane, nn_3, selLds[3]);
    else {
        int t = tid - 256;                              // waves 4-7 clear buf 0
        #pragma unroll
        for (int i = 0; i < 16; ++i) hb[t + (i << 8)] = 0;
    }
    __syncthreads();                                    // B5

#define SEL1(r) unsigned d1_##r = rflu(selLds[r][0]); nn_##r = rflu(selLds[r][1]); \
    float C2_##r = 1023.0f * C1_##r, B2_##r = 1023.0f * (B1_##r - (float)d1_##r);
    ROWS(SEL1)

    // post-scan1: refine on eqc bits only, pass-2 atomics (buf 0)
    unsigned neq = 0;
    #pragma unroll
    for (int j = 0; j < 8; ++j) {
#define PS1(r) if ((eqc >> (j + 8 * r)) & 1u) { unsigned i1 = idx_of(s##r[j], C1_##r, B1_##r); \
        if (i1 > d1_##r) abv |= 1u << (j + 8 * r); \
        else if (i1 == d1_##r) { neq |= 1u << (j + 8 * r); \
            atomicAdd(&hist[0][r][idx_of(s##r[j], C2_##r, B2_##r)], 1u); } }
        ROWS(PS1)
    }
    __syncthreads();                                    // B6
    if (wv == 0)      scan1024(hist[0][0], lane, nn_0, selLds[0]);
    else if (wv == 1) scan1024(hist[0][1], lane, nn_1, selLds[1]);
    else if (wv == 2) scan1024(hist[0][2], lane, nn_2, selLds[2]);
    else if (wv == 3) scan1024(hist[0][3], lane, nn_3, selLds[3]);
    __syncthreads();                                    // B7

#define SEL2(r) unsigned d2_##r = rflu(selLds[r][0]); unsigned ne_##r = rflu(selLds[r][1]); \
    unsigned ct_##r = rflu(selLds[r][2]); float se_##r = (float)ne_##r / (float)ct_##r;
    ROWS(SEL2)

    // post-scan2: finalize abv/tie
    unsigned tie = 0;
    #pragma unroll
    for (int j = 0; j < 8; ++j) {
#define PS2(r) if ((neq >> (j + 8 * r)) & 1u) { unsigned i2 = idx_of(s##r[j], C2_##r, B2_##r); \
        if (i2 > d2_##r) abv |= 1u << (j + 8 * r); else if (i2 == d2_##r) tie |= 1u << (j + 8 * r); }
        ROWS(PS2)
    }

    // Phase 3: softmax + PV; V loaded once, shared by 4 rows
#define DECLACC(r) float dn##r = 0.f; float4 ac##r = {0.f, 0.f, 0.f, 0.f};
    ROWS(DECLACC)
#define P3B(r, WEXPR) { float x = s##r[j] - MX_##r; float w = (WEXPR); \
    w = ((abv >> (j + 8 * r)) & 1u) ? w : (((tie >> (j + 8 * r)) & 1u) ? w * se_##r : 0.f); \
    dn##r += w; ac##r.x = fmaf(w, vv.x, ac##r.x); ac##r.y = fmaf(w, vv.y, ac##r.y); \
    ac##r.z = fmaf(w, vv.z, ac##r.z); ac##r.w = fmaf(w, vv.w, ac##r.w); }
    if (taylor) {
        // exp2(x) ~= 1 + x(ln2 + x ln2^2/2), |x| < 0.04 -> rel err < 4e-6
        #pragma unroll
        for (int j = 0; j < 8; ++j) {
            float4 vv = vb4[tid + (j << 9)];
#define P3T(r) P3B(r, fmaf(x, fmaf(x, TC2, TC1), 1.0f))
            ROWS(P3T)
        }
    } else {
        #pragma unroll
        for (int j = 0; j < 8; ++j) {
            float4 vv = vb4[tid + (j << 9)];
#define P3E(r) P3B(r, __builtin_amdgcn_exp2f(x))
            ROWS(P3E)
        }
    }

    #pragma unroll
    for (int off = 32; off > 0; off >>= 1) {
#define REDF(r) dn##r += __shfl_down(dn##r, off, 64); \
        ac##r.x += __shfl_down(ac##r.x, off, 64); ac##r.y += __shfl_down(ac##r.y, off, 64); \
        ac##r.z += __shfl_down(ac##r.z, off, 64); ac##r.w += __shfl_down(ac##r.w, off, 64);
        ROWS(REDF)
    }
    if (lane == 0) {
#define WRED(r) { float* p = red[wv][r]; p[0] = dn##r; p[1] = ac##r.x; p[2] = ac##r.y; \
        p[3] = ac##r.z; p[4] = ac##r.w; }
        ROWS(WRED)
    }
    __syncthreads();                                    // B8
    if (tid < 4) {
        int r = tid;
        float D = 0, o0 = 0, o1 = 0, o2 = 0, o3 = 0;
        #pragma unroll
        for (int w = 0; w < 8; ++w) {
            const float* p = red[w][r];
            D += p[0]; o0 += p[1]; o1 += p[2]; o2 += p[3]; o3 += p[4];
        }
        float invD = 1.f / D;
        int n = n0 + r;
        outp[((head << 2) + 0) * NTOK + n] = o0 * invD;
        outp[((head << 2) + 1) * NTOK + n] = o1 * invD;
        outp[((head << 2) + 2) * NTOK + n] = o2 * invD;
        outp[((head << 2) + 3) * NTOK + n] = o3 * invD;
    }
}

// out[o][p] = sum_ch wp[o][ch] * ao[head(ch)*4+cph(ch)][p*4 + t(ch)], ch = t*32 + head*4 + cph
__global__ void k_proj(const float* __restrict__ ao, const float* __restrict__ wp,
                       float* __restrict__ out) {
    __shared__ float chin[128];
    int p = blockIdx.x;
    int tid = threadIdx.x;       // 128
    int t = tid >> 5;
    int c = tid & 31;
    chin[tid] = ao[c * NTOK + (p << 2) + t];
    __syncthreads();
    const float* wr = wp + tid * 128;
    float acc = 0.f;
    #pragma unroll 8
    for (int ch = 0; ch < 128; ++ch) acc = fmaf(wr[ch], chin[ch], acc);
    out[tid * 1024 + p] = acc;
}

extern "C" void kernel_launch(void* const* d_in, const int* in_sizes, int n_in,
                              void* d_out, int out_size, void* d_ws, size_t ws_size,
                              hipStream_t stream) {
    const float* x    = (const float*)d_in[0];
    const float* temp = (const float*)d_in[1];
    const float* wq   = (const float*)d_in[2];
    const float* wdw  = (const float*)d_in[3];
    const float* wp   = (const float*)d_in[4];
    float* out = (float*)d_out;
    float* ws = (float*)d_ws;

    float* qh = ws;                      // [head][n][4] = 131072 floats
    float* kh = qh + 131072;
    float* vh = kh + 131072;
    float* ao = vh + 131072;             // [c][n]
    float* ssb = ao + 131072;            // 64 floats

    hipMemsetAsync(ssb, 0, 64 * sizeof(float), stream);
    k_fused<<<384,  256, 0, stream>>>(x, wq, wdw, qh, kh, vh, ssb);
    k_attn <<<8192, 512, 0, stream>>>(qh, kh, vh, ssb, temp, ao);
    k_proj <<<1024, 128, 0, stream>>>(ao, wp, out);
}

// Round 14
// 318.513 us; speedup vs baseline: 1.1813x; 1.1813x over previous
//
#include <hip/hip_runtime.h>

#define NTOK 4096
#define KK   3276   // int(4096 * 0.8)
#define NB   1024
#define LOG2E 1.4426950408889634f
#define TC1 0.69314718056f     // ln2
#define TC2 0.24022650696f     // ln2^2/2

typedef float f32x16 __attribute__((ext_vector_type(16)));

__device__ __forceinline__ float rflf(float x) {
    return __int_as_float(__builtin_amdgcn_readfirstlane(__float_as_int(x)));
}
__device__ __forceinline__ unsigned rflu(unsigned x) {
    return (unsigned)__builtin_amdgcn_readfirstlane((int)x);
}
// fixed-point bin index; identical instruction sequence at every use site
__device__ __forceinline__ unsigned idx_of(float s, float C, float B) {
    unsigned i = (unsigned)(fmaf(s, C, B));   // v_cvt_u32_f32 clamps <0 -> 0
    return i > 1023u ? 1023u : i;
}

// one wave scans a 1024-bin histogram: find largest bin `dig` such that
// suffix-count(dig) >= need; write {dig, need - suffix(dig+1), count(dig)}.
__device__ __forceinline__ void scan1024(const unsigned* __restrict__ h, int lane,
                                         unsigned need, unsigned* __restrict__ selp) {
    const uint4* h4 = (const uint4*)(h + (lane << 4));
    uint4 u0 = h4[0], u1 = h4[1], u2 = h4[2], u3 = h4[3];
    unsigned f15 = u3.w;
    unsigned f14 = u3.z + f15, f13 = u3.y + f14, f12 = u3.x + f13;
    unsigned f11 = u2.w + f12, f10 = u2.z + f11, f9 = u2.y + f10, f8 = u2.x + f9;
    unsigned f7 = u1.w + f8, f6 = u1.z + f7, f5 = u1.y + f6, f4 = u1.x + f5;
    unsigned f3 = u0.w + f4, f2 = u0.z + f3, f1 = u0.y + f2, f0 = u0.x + f1;
    unsigned ls = f0;
    unsigned S = ls;
    #pragma unroll
    for (int off = 1; off < 64; off <<= 1) {
        unsigned v = __shfl_down(S, off, 64);
        if (lane + off < 64) S += v;
    }
    unsigned above = S - ls;       // suffix count of lanes > this lane
    if (above < need && above + ls >= need) {
        unsigned kk = 0, selCur = f0, selNext = f1;
        #define STEP(k, fk, fk1) if (above + (fk) >= need) { kk = k; selCur = (fk); selNext = (fk1); }
        STEP(0, f0, f1)  STEP(1, f1, f2)   STEP(2, f2, f3)   STEP(3, f3, f4)
        STEP(4, f4, f5)  STEP(5, f5, f6)   STEP(6, f6, f7)   STEP(7, f7, f8)
        STEP(8, f8, f9)  STEP(9, f9, f10)  STEP(10, f10, f11) STEP(11, f11, f12)
        STEP(12, f12, f13) STEP(13, f13, f14) STEP(14, f14, f15) STEP(15, f15, 0u)
        #undef STEP
        selp[0] = (unsigned)(lane << 4) + kk;
        selp[1] = need - (above + selNext);
        selp[2] = selCur - selNext;
    }
}

// Fused: pointwise-over-t conv + depthwise 3x3 + scatter to [head][n][4] + sum-of-squares
__global__ __launch_bounds__(256) void k_fused(const float* __restrict__ x,
                                               const float* __restrict__ wq,
                                               const float* __restrict__ wdw,
                                               float* __restrict__ qh,
                                               float* __restrict__ kh,
                                               float* __restrict__ vh,
                                               float* __restrict__ ss) {
    __shared__ float p[1024];
    int b = blockIdx.x;
    int o = b >> 5, c = b & 31;
    int tid = threadIdx.x;
    float w0 = wq[o * 4 + 0], w1 = wq[o * 4 + 1], w2 = wq[o * 4 + 2], w3 = wq[o * 4 + 3];
    const float* x0 = x + (c << 10);
    #pragma unroll
    for (int r = 0; r < 4; ++r) {
        int hw = tid + (r << 8);
        float a = w0 * x0[hw];
        a = fmaf(w1, x0[(32 << 10) + hw], a);
        a = fmaf(w2, x0[(64 << 10) + hw], a);
        a = fmaf(w3, x0[(96 << 10) + hw], a);
        p[hw] = a;
    }
    __syncthreads();
    float wd[9];
    #pragma unroll
    for (int i = 0; i < 9; ++i) wd[i] = wdw[o * 9 + i];
    int g = o >> 2, t = o & 3;
    int head = c >> 2, cph = c & 3;
    float* dst = (g == 0) ? qh : (g == 1) ? kh : vh;
    float ssum = 0.f;
    #pragma unroll
    for (int r = 0; r < 4; ++r) {
        int hw = tid + (r << 8);
        int wcol = hw & 31, hrow = hw >> 5;
        float a = 0.f;
        #pragma unroll
        for (int dy = -1; dy <= 1; ++dy) {
            int hh = hrow + dy;
            if (hh < 0 || hh > 31) continue;
            #pragma unroll
            for (int dx = -1; dx <= 1; ++dx) {
                int ww = wcol + dx;
                if (ww < 0 || ww > 31) continue;
                a = fmaf(wd[(dy + 1) * 3 + (dx + 1)], p[hh * 32 + ww], a);
            }
        }
        int n = (hw << 2) + t;
        dst[(((head << 12) + n) << 2) + cph] = a;
        ssum = fmaf(a, a, ssum);
    }
    if (g < 2) {
        #pragma unroll
        for (int off = 32; off > 0; off >>= 1) ssum += __shfl_down(ssum, off, 64);
        if ((tid & 63) == 0) atomicAdd(&ss[g * 32 + c], ssum);
    }
}

// One block per (head, 2 rows). Scores (log2-scaled) in registers; adaptive
// fixed-point 2-pass x 1024-bin (20-bit) radix select; classification bitmasks;
// Taylor exp2 under wave-uniform small-range guard. 6 barriers.
__global__ __launch_bounds__(256, 5) void k_attn(const float* __restrict__ qh,
                                                 const float* __restrict__ kh,
                                                 const float* __restrict__ vh,
                                                 const float* __restrict__ ss,
                                                 const float* __restrict__ temp,
                                                 float* __restrict__ outp) {
    __shared__ __align__(16) unsigned hist[2][2][NB];   // [pass][row][bin] 16 KB
    __shared__ float mm[4][4];
    __shared__ unsigned selLds[2][3];
    __shared__ float red[4][10];

    int bid = blockIdx.x;
    int head = bid >> 11;
    int n0 = (bid & 2047) << 1;
    int tid = threadIdx.x;
    int lane = tid & 63;
    int wv = tid >> 6;

    // clear both histogram buffers (4096 words)
    unsigned* hb = &hist[0][0][0];
    #pragma unroll
    for (int i = 0; i < 16; ++i) hb[tid + (i << 8)] = 0;

    // per-cph combined scale: log2e * temp / (||q_c|| * ||k_c||), folded into q.
    float tempv = temp[head] * LOG2E;
    const float* sq = ss + head * 4;
    const float* sk = ss + 32 + head * 4;
    float f0 = tempv / (fmaxf(sqrtf(sq[0]), 1e-12f) * fmaxf(sqrtf(sk[0]), 1e-12f));
    float f1 = tempv / (fmaxf(sqrtf(sq[1]), 1e-12f) * fmaxf(sqrtf(sk[1]), 1e-12f));
    float f2 = tempv / (fmaxf(sqrtf(sq[2]), 1e-12f) * fmaxf(sqrtf(sk[2]), 1e-12f));
    float f3 = tempv / (fmaxf(sqrtf(sq[3]), 1e-12f) * fmaxf(sqrtf(sk[3]), 1e-12f));

    const float4* kb4 = (const float4*)kh + (head << 12);
    const float4* vb4 = (const float4*)vh + (head << 12);
    float4 qa = ((const float4*)qh)[(head << 12) + n0];
    float4 qb = ((const float4*)qh)[(head << 12) + n0 + 1];
    qa.x *= f0; qa.y *= f1; qa.z *= f2; qa.w *= f3;
    qb.x *= f0; qb.y *= f1; qb.z *= f2; qb.w *= f3;

    // Phase 1: scores in registers + per-row min/max
    f32x16 sA, sB;
    float mnA = INFINITY, mxA = -INFINITY, mnB = INFINITY, mxB = -INFINITY;
    #pragma unroll
    for (int j = 0; j < 16; ++j) {
        float4 kv = kb4[tid + (j << 8)];
        float va = fmaf(qa.w, kv.w, fmaf(qa.z, kv.z, fmaf(qa.y, kv.y, qa.x * kv.x)));
        float vb = fmaf(qb.w, kv.w, fmaf(qb.z, kv.z, fmaf(qb.y, kv.y, qb.x * kv.x)));
        sA[j] = va; sB[j] = vb;
        mnA = fminf(mnA, va); mxA = fmaxf(mxA, va);
        mnB = fminf(mnB, vb); mxB = fmaxf(mxB, vb);
    }
    #pragma unroll
    for (int off = 32; off > 0; off >>= 1) {
        mnA = fminf(mnA, __shfl_down(mnA, off, 64));
        mxA = fmaxf(mxA, __shfl_down(mxA, off, 64));
        mnB = fminf(mnB, __shfl_down(mnB, off, 64));
        mxB = fmaxf(mxB, __shfl_down(mxB, off, 64));
    }
    if (lane == 0) { mm[wv][0] = mnA; mm[wv][1] = mxA; mm[wv][2] = mnB; mm[wv][3] = mxB; }
    __syncthreads();                               // B1: clears + mm visible

    mnA = fminf(fminf(mm[0][0], mm[1][0]), fminf(mm[2][0], mm[3][0]));
    mxA = fmaxf(fmaxf(mm[0][1], mm[1][1]), fmaxf(mm[2][1], mm[3][1]));
    mnB = fminf(fminf(mm[0][2], mm[1][2]), fminf(mm[2][2], mm[3][2]));
    mxB = fmaxf(fmaxf(mm[0][3], mm[1][3]), fmaxf(mm[2][3], mm[3][3]));
    float rgA = fmaxf(mxA - mnA, 1e-30f);
    float rgB = fmaxf(mxB - mnB, 1e-30f);
    float C0A = rflf(1023.0f / rgA);
    float C0B = rflf(1023.0f / rgB);
    float B0A = rflf(-mnA * C0A);
    float B0B = rflf(-mnB * C0B);
    float MXA = rflf(mxA), MXB = rflf(mxB);
    bool taylor = fmaxf(rflf(rgA), rflf(rgB)) < 0.04f;   // wave-uniform

    // pass 0 atomics (buf 0)
    #pragma unroll
    for (int j = 0; j < 16; ++j) {
        atomicAdd(&hist[0][0][idx_of(sA[j], C0A, B0A)], 1u);
        atomicAdd(&hist[0][1][idx_of(sB[j], C0B, B0B)], 1u);
    }
    __syncthreads();                               // B2
    if (wv == 0)      scan1024(hist[0][0], lane, KK, selLds[0]);
    else if (wv == 1) scan1024(hist[0][1], lane, KK, selLds[1]);
    __syncthreads();                               // B3
    unsigned d0A = rflu(selLds[0][0]), nA = rflu(selLds[0][1]);
    unsigned d0B = rflu(selLds[1][0]), nB = rflu(selLds[1][1]);
    float C1A = 1023.0f * C0A, B1A = 1023.0f * (B0A - (float)d0A);
    float C1B = 1023.0f * C0B, B1B = 1023.0f * (B0B - (float)d0B);

    // post-scan0: build abv/eqc masks, issue pass-1 atomics (buf 1)
    unsigned abvA = 0, abvB = 0, eqcA = 0, eqcB = 0;
    #pragma unroll
    for (int j = 0; j < 16; ++j) {
        unsigned i0 = idx_of(sA[j], C0A, B0A);
        if (i0 > d0A) abvA |= (1u << j);
        else if (i0 == d0A) {
            eqcA |= (1u << j);
            atomicAdd(&hist[1][0][idx_of(sA[j], C1A, B1A)], 1u);
        }
        unsigned k0 = idx_of(sB[j], C0B, B0B);
        if (k0 > d0B) abvB |= (1u << j);
        else if (k0 == d0B) {
            eqcB |= (1u << j);
            atomicAdd(&hist[1][1][idx_of(sB[j], C1B, B1B)], 1u);
        }
    }
    __syncthreads();                               // B4
    if (wv == 0)      scan1024(hist[1][0], lane, nA, selLds[0]);
    else if (wv == 1) scan1024(hist[1][1], lane, nB, selLds[1]);
    __syncthreads();                               // B5
    unsigned d1A = rflu(selLds[0][0]), neA = rflu(selLds[0][1]), ctA = rflu(selLds[0][2]);
    unsigned d1B = rflu(selLds[1][0]), neB = rflu(selLds[1][1]), ctB = rflu(selLds[1][2]);
    float seA = (float)neA / (float)ctA;
    float seB = (float)neB / (float)ctB;

    // finalize: refine eqc candidates against pass-1 bin (20-bit tie boundary)
    unsigned tieA = 0, tieB = 0;
    #pragma unroll
    for (int j = 0; j < 16; ++j) {
        if ((eqcA >> j) & 1u) {
            unsigned i1 = idx_of(sA[j], C1A, B1A);
            if (i1 > d1A) abvA |= (1u << j);
            else if (i1 == d1A) tieA |= (1u << j);
        }
        if ((eqcB >> j) & 1u) {
            unsigned i1 = idx_of(sB[j], C1B, B1B);
            if (i1 > d1B) abvB |= (1u << j);
            else if (i1 == d1B) tieB |= (1u << j);
        }
    }

    // Phase 3: softmax + PV via mask bits; Taylor exp2 when range is tiny
    float dA = 0.f, dB = 0.f;
    float4 A = {0.f, 0.f, 0.f, 0.f}, Bv = {0.f, 0.f, 0.f, 0.f};
#define P3PAIR(WA, WB) { \
        float wa = (WA); \
        wa = ((abvA >> j) & 1u) ? wa : (((tieA >> j) & 1u) ? wa * seA : 0.f); \
        dA += wa; \
        A.x = fmaf(wa, vv.x, A.x); A.y = fmaf(wa, vv.y, A.y); \
        A.z = fmaf(wa, vv.z, A.z); A.w = fmaf(wa, vv.w, A.w); \
        float wb = (WB); \
        wb = ((abvB >> j) & 1u) ? wb : (((tieB >> j) & 1u) ? wb * seB : 0.f); \
        dB += wb; \
        Bv.x = fmaf(wb, vv.x, Bv.x); Bv.y = fmaf(wb, vv.y, Bv.y); \
        Bv.z = fmaf(wb, vv.z, Bv.z); Bv.w = fmaf(wb, vv.w, Bv.w); }
    if (taylor) {
        // exp2(x) ~= 1 + x(ln2 + x ln2^2/2): rel err < 4e-6 for |x| < 0.04
        #pragma unroll
        for (int j = 0; j < 16; ++j) {
            float4 vv = vb4[tid + (j << 8)];
            float xa = sA[j] - MXA, xb = sB[j] - MXB;
            P3PAIR(fmaf(xa, fmaf(xa, TC2, TC1), 1.0f),
                   fmaf(xb, fmaf(xb, TC2, TC1), 1.0f))
        }
    } else {
        #pragma unroll
        for (int j = 0; j < 16; ++j) {
            float4 vv = vb4[tid + (j << 8)];
            float xa = sA[j] - MXA, xb = sB[j] - MXB;
            P3PAIR(__builtin_amdgcn_exp2f(xa), __builtin_amdgcn_exp2f(xb))
        }
    }
#undef P3PAIR
    #pragma unroll
    for (int off = 32; off > 0; off >>= 1) {
        dA += __shfl_down(dA, off, 64);
        A.x += __shfl_down(A.x, off, 64); A.y += __shfl_down(A.y, off, 64);
        A.z += __shfl_down(A.z, off, 64); A.w += __shfl_down(A.w, off, 64);
        dB += __shfl_down(dB, off, 64);
        Bv.x += __shfl_down(Bv.x, off, 64); Bv.y += __shfl_down(Bv.y, off, 64);
        Bv.z += __shfl_down(Bv.z, off, 64); Bv.w += __shfl_down(Bv.w, off, 64);
    }
    if (lane == 0) {
        float* r = red[wv];
        r[0] = dA; r[1] = A.x; r[2] = A.y; r[3] = A.z; r[4] = A.w;
        r[5] = dB; r[6] = Bv.x; r[7] = Bv.y; r[8] = Bv.z; r[9] = Bv.w;
    }
    __syncthreads();                               // B6
    if (tid < 2) {
        int base = tid * 5;
        float D  = red[0][base] + red[1][base] + red[2][base] + red[3][base];
        float o0 = red[0][base + 1] + red[1][base + 1] + red[2][base + 1] + red[3][base + 1];
        float o1 = red[0][base + 2] + red[1][base + 2] + red[2][base + 2] + red[3][base + 2];
        float o2 = red[0][base + 3] + red[1][base + 3] + red[2][base + 3] + red[3][base + 3];
        float o3 = red[0][base + 4] + red[1][base + 4] + red[2][base + 4] + red[3][base + 4];
        float invD = 1.f / D;
        int n = n0 + tid;
        outp[((head << 2) + 0) * NTOK + n] = o0 * invD;
        outp[((head << 2) + 1) * NTOK + n] = o1 * invD;
        outp[((head << 2) + 2) * NTOK + n] = o2 * invD;
        outp[((head << 2) + 3) * NTOK + n] = o3 * invD;
    }
}

// out[o][p] = sum_ch wp[o][ch] * ao[head(ch)*4+cph(ch)][p*4 + t(ch)], ch = t*32 + head*4 + cph
__global__ void k_proj(const float* __restrict__ ao, const float* __restrict__ wp,
                       float* __restrict__ out) {
    __shared__ float chin[128];
    int p = blockIdx.x;
    int tid = threadIdx.x;       // 128
    int t = tid >> 5;
    int c = tid & 31;
    chin[tid] = ao[c * NTOK + (p << 2) + t];
    __syncthreads();
    const float* wr = wp + tid * 128;
    float acc = 0.f;
    #pragma unroll 8
    for (int ch = 0; ch < 128; ++ch) acc = fmaf(wr[ch], chin[ch], acc);
    out[tid * 1024 + p] = acc;
}

extern "C" void kernel_launch(void* const* d_in, const int* in_sizes, int n_in,
                              void* d_out, int out_size, void* d_ws, size_t ws_size,
                              hipStream_t stream) {
    const float* x    = (const float*)d_in[0];
    const float* temp = (const float*)d_in[1];
    const float* wq   = (const float*)d_in[2];
    const float* wdw  = (const float*)d_in[3];
    const float* wp   = (const float*)d_in[4];
    float* out = (float*)d_out;
    float* ws = (float*)d_ws;

    float* qh = ws;                      // [head][n][4] = 131072 floats
    float* kh = qh + 131072;
    float* vh = kh + 131072;
    float* ao = vh + 131072;             // [c][n]
    float* ssb = ao + 131072;            // 64 floats

    hipMemsetAsync(ssb, 0, 64 * sizeof(float), stream);
    k_fused<<<384,   256, 0, stream>>>(x, wq, wdw, qh, kh, vh, ssb);
    k_attn <<<16384, 256, 0, stream>>>(qh, kh, vh, ssb, temp, ao);
    k_proj <<<1024,  128, 0, stream>>>(ao, wp, out);
}

// Round 15
// 260.499 us; speedup vs baseline: 1.4444x; 1.2227x over previous
//
#include <hip/hip_runtime.h>

#define NTOK 4096
#define KK   3276   // int(4096 * 0.8)
#define NB   1024
#define LOG2E 1.4426950408889634f

typedef float f32x16 __attribute__((ext_vector_type(16)));

__device__ __forceinline__ float rflf(float x) {
    return __int_as_float(__builtin_amdgcn_readfirstlane(__float_as_int(x)));
}
__device__ __forceinline__ unsigned rflu(unsigned x) {
    return (unsigned)__builtin_amdgcn_readfirstlane((int)x);
}
// fixed-point bin index; identical instruction sequence at every use site
__device__ __forceinline__ unsigned idx_of(float s, float C, float B) {
    unsigned i = (unsigned)(fmaf(s, C, B));   // v_cvt_u32_f32 clamps <0 -> 0
    return i > 1023u ? 1023u : i;
}

// one wave scans a 1024-bin histogram: find largest bin `dig` such that
// suffix-count(dig) >= need; write {dig, need - suffix(dig+1), count(dig)}.
__device__ __forceinline__ void scan1024(const unsigned* __restrict__ h, int lane,
                                         unsigned need, unsigned* __restrict__ selp) {
    const uint4* h4 = (const uint4*)(h + (lane << 4));
    uint4 u0 = h4[0], u1 = h4[1], u2 = h4[2], u3 = h4[3];
    unsigned f15 = u3.w;
    unsigned f14 = u3.z + f15, f13 = u3.y + f14, f12 = u3.x + f13;
    unsigned f11 = u2.w + f12, f10 = u2.z + f11, f9 = u2.y + f10, f8 = u2.x + f9;
    unsigned f7 = u1.w + f8, f6 = u1.z + f7, f5 = u1.y + f6, f4 = u1.x + f5;
    unsigned f3 = u0.w + f4, f2 = u0.z + f3, f1 = u0.y + f2, f0 = u0.x + f1;
    unsigned ls = f0;
    unsigned S = ls;
    #pragma unroll
    for (int off = 1; off < 64; off <<= 1) {
        unsigned v = __shfl_down(S, off, 64);
        if (lane + off < 64) S += v;
    }
    unsigned above = S - ls;       // suffix count of lanes > this lane
    if (above < need && above + ls >= need) {
        unsigned kk = 0, selCur = f0, selNext = f1;
        #define STEP(k, fk, fk1) if (above + (fk) >= need) { kk = k; selCur = (fk); selNext = (fk1); }
        STEP(0, f0, f1)  STEP(1, f1, f2)   STEP(2, f2, f3)   STEP(3, f3, f4)
        STEP(4, f4, f5)  STEP(5, f5, f6)   STEP(6, f6, f7)   STEP(7, f7, f8)
        STEP(8, f8, f9)  STEP(9, f9, f10)  STEP(10, f10, f11) STEP(11, f11, f12)
        STEP(12, f12, f13) STEP(13, f13, f14) STEP(14, f14, f15) STEP(15, f15, 0u)
        #undef STEP
        selp[0] = (unsigned)(lane << 4) + kk;
        selp[1] = need - (above + selNext);
        selp[2] = selCur - selNext;
    }
}

// Fused: pointwise-over-t conv + depthwise 3x3 + scatter to [head][n][4] + sum-of-squares
__global__ __launch_bounds__(256) void k_fused(const float* __restrict__ x,
                                               const float* __restrict__ wq,
                                               const float* __restrict__ wdw,
                                               float* __restrict__ qh,
                                               float* __restrict__ kh,
                                               float* __restrict__ vh,
                                               float* __restrict__ ss) {
    __shared__ float p[1024];
    int b = blockIdx.x;
    int o = b >> 5, c = b & 31;
    int tid = threadIdx.x;
    float w0 = wq[o * 4 + 0], w1 = wq[o * 4 + 1], w2 = wq[o * 4 + 2], w3 = wq[o * 4 + 3];
    const float* x0 = x + (c << 10);
    #pragma unroll
    for (int r = 0; r < 4; ++r) {
        int hw = tid + (r << 8);
        float a = w0 * x0[hw];
        a = fmaf(w1, x0[(32 << 10) + hw], a);
        a = fmaf(w2, x0[(64 << 10) + hw], a);
        a = fmaf(w3, x0[(96 << 10) + hw], a);
        p[hw] = a;
    }
    __syncthreads();
    float wd[9];
    #pragma unroll
    for (int i = 0; i < 9; ++i) wd[i] = wdw[o * 9 + i];
    int g = o >> 2, t = o & 3;
    int head = c >> 2, cph = c & 3;
    float* dst = (g == 0) ? qh : (g == 1) ? kh : vh;
    float ssum = 0.f;
    #pragma unroll
    for (int r = 0; r < 4; ++r) {
        int hw = tid + (r << 8);
        int wcol = hw & 31, hrow = hw >> 5;
        float a = 0.f;
        #pragma unroll
        for (int dy = -1; dy <= 1; ++dy) {
            int hh = hrow + dy;
            if (hh < 0 || hh > 31) continue;
            #pragma unroll
            for (int dx = -1; dx <= 1; ++dx) {
                int ww = wcol + dx;
                if (ww < 0 || ww > 31) continue;
                a = fmaf(wd[(dy + 1) * 3 + (dx + 1)], p[hh * 32 + ww], a);
            }
        }
        int n = (hw << 2) + t;
        dst[(((head << 12) + n) << 2) + cph] = a;
        ssum = fmaf(a, a, ssum);
    }
    if (g < 2) {
        #pragma unroll
        for (int off = 32; off > 0; off >>= 1) ssum += __shfl_down(ssum, off, 64);
        if ((tid & 63) == 0) atomicAdd(&ss[g * 32 + c], ssum);
    }
}

// One block per (head, 2 rows). Scores (log2-scaled) in registers; adaptive
// fixed-point 2-pass x 1024-bin (20-bit) radix select; classification bitmasks;
// single P3 loop (no branch duplication). 6 barriers.
__global__ __launch_bounds__(256, 5) void k_attn(const float* __restrict__ qh,
                                                 const float* __restrict__ kh,
                                                 const float* __restrict__ vh,
                                                 const float* __restrict__ ss,
                                                 const float* __restrict__ temp,
                                                 float* __restrict__ outp) {
    __shared__ __align__(16) unsigned hist[2][2][NB];   // [pass][row][bin] 16 KB
    __shared__ float mm[4][4];
    __shared__ unsigned selLds[2][3];
    __shared__ float red[4][10];

    int bid = blockIdx.x;
    int head = bid >> 11;
    int n0 = (bid & 2047) << 1;
    int tid = threadIdx.x;
    int lane = tid & 63;
    int wv = tid >> 6;

    // clear both histogram buffers (4096 words)
    unsigned* hb = &hist[0][0][0];
    #pragma unroll
    for (int i = 0; i < 16; ++i) hb[tid + (i << 8)] = 0;

    // per-cph combined scale: log2e * temp / (||q_c|| * ||k_c||), folded into q.
    float tempv = temp[head] * LOG2E;
    const float* sq = ss + head * 4;
    const float* sk = ss + 32 + head * 4;
    float f0 = tempv / (fmaxf(sqrtf(sq[0]), 1e-12f) * fmaxf(sqrtf(sk[0]), 1e-12f));
    float f1 = tempv / (fmaxf(sqrtf(sq[1]), 1e-12f) * fmaxf(sqrtf(sk[1]), 1e-12f));
    float f2 = tempv / (fmaxf(sqrtf(sq[2]), 1e-12f) * fmaxf(sqrtf(sk[2]), 1e-12f));
    float f3 = tempv / (fmaxf(sqrtf(sq[3]), 1e-12f) * fmaxf(sqrtf(sk[3]), 1e-12f));

    const float4* kb4 = (const float4*)kh + (head << 12);
    const float4* vb4 = (const float4*)vh + (head << 12);
    float4 qa = ((const float4*)qh)[(head << 12) + n0];
    float4 qb = ((const float4*)qh)[(head << 12) + n0 + 1];
    qa.x *= f0; qa.y *= f1; qa.z *= f2; qa.w *= f3;
    qb.x *= f0; qb.y *= f1; qb.z *= f2; qb.w *= f3;

    // Phase 1: scores in registers + per-row min/max
    f32x16 sA, sB;
    float mnA = INFINITY, mxA = -INFINITY, mnB = INFINITY, mxB = -INFINITY;
    #pragma unroll
    for (int j = 0; j < 16; ++j) {
        float4 kv = kb4[tid + (j << 8)];
        float va = fmaf(qa.w, kv.w, fmaf(qa.z, kv.z, fmaf(qa.y, kv.y, qa.x * kv.x)));
        float vb = fmaf(qb.w, kv.w, fmaf(qb.z, kv.z, fmaf(qb.y, kv.y, qb.x * kv.x)));
        sA[j] = va; sB[j] = vb;
        mnA = fminf(mnA, va); mxA = fmaxf(mxA, va);
        mnB = fminf(mnB, vb); mxB = fmaxf(mxB, vb);
    }
    #pragma unroll
    for (int off = 32; off > 0; off >>= 1) {
        mnA = fminf(mnA, __shfl_down(mnA, off, 64));
        mxA = fmaxf(mxA, __shfl_down(mxA, off, 64));
        mnB = fminf(mnB, __shfl_down(mnB, off, 64));
        mxB = fmaxf(mxB, __shfl_down(mxB, off, 64));
    }
    if (lane == 0) { mm[wv][0] = mnA; mm[wv][1] = mxA; mm[wv][2] = mnB; mm[wv][3] = mxB; }
    __syncthreads();                               // B1: clears + mm visible

    mnA = fminf(fminf(mm[0][0], mm[1][0]), fminf(mm[2][0], mm[3][0]));
    mxA = fmaxf(fmaxf(mm[0][1], mm[1][1]), fmaxf(mm[2][1], mm[3][1]));
    mnB = fminf(fminf(mm[0][2], mm[1][2]), fminf(mm[2][2], mm[3][2]));
    mxB = fmaxf(fmaxf(mm[0][3], mm[1][3]), fmaxf(mm[2][3], mm[3][3]));
    float C0A = rflf(1023.0f / fmaxf(mxA - mnA, 1e-30f));
    float C0B = rflf(1023.0f / fmaxf(mxB - mnB, 1e-30f));
    float B0A = rflf(-mnA * C0A);
    float B0B = rflf(-mnB * C0B);
    float MXA = rflf(mxA), MXB = rflf(mxB);

    // pass 0 atomics (buf 0)
    #pragma unroll
    for (int j = 0; j < 16; ++j) {
        atomicAdd(&hist[0][0][idx_of(sA[j], C0A, B0A)], 1u);
        atomicAdd(&hist[0][1][idx_of(sB[j], C0B, B0B)], 1u);
    }
    __syncthreads();                               // B2
    if (wv == 0)      scan1024(hist[0][0], lane, KK, selLds[0]);
    else if (wv == 1) scan1024(hist[0][1], lane, KK, selLds[1]);
    __syncthreads();                               // B3
    unsigned d0A = rflu(selLds[0][0]), nA = rflu(selLds[0][1]);
    unsigned d0B = rflu(selLds[1][0]), nB = rflu(selLds[1][1]);
    float C1A = 1023.0f * C0A, B1A = 1023.0f * (B0A - (float)d0A);
    float C1B = 1023.0f * C0B, B1B = 1023.0f * (B0B - (float)d0B);

    // post-scan0: build abv/eqc masks, issue pass-1 atomics (buf 1)
    unsigned abvA = 0, abvB = 0, eqcA = 0, eqcB = 0;
    #pragma unroll
    for (int j = 0; j < 16; ++j) {
        unsigned i0 = idx_of(sA[j], C0A, B0A);
        if (i0 > d0A) abvA |= (1u << j);
        else if (i0 == d0A) {
            eqcA |= (1u << j);
            atomicAdd(&hist[1][0][idx_of(sA[j], C1A, B1A)], 1u);
        }
        unsigned k0 = idx_of(sB[j], C0B, B0B);
        if (k0 > d0B) abvB |= (1u << j);
        else if (k0 == d0B) {
            eqcB |= (1u << j);
            atomicAdd(&hist[1][1][idx_of(sB[j], C1B, B1B)], 1u);
        }
    }
    __syncthreads();                               // B4
    if (wv == 0)      scan1024(hist[1][0], lane, nA, selLds[0]);
    else if (wv == 1) scan1024(hist[1][1], lane, nB, selLds[1]);
    __syncthreads();                               // B5
    unsigned d1A = rflu(selLds[0][0]), neA = rflu(selLds[0][1]), ctA = rflu(selLds[0][2]);
    unsigned d1B = rflu(selLds[1][0]), neB = rflu(selLds[1][1]), ctB = rflu(selLds[1][2]);
    float seA = (float)neA / (float)ctA;
    float seB = (float)neB / (float)ctB;

    // finalize: refine eqc candidates against pass-1 bin (20-bit tie boundary)
    unsigned tieA = 0, tieB = 0;
    #pragma unroll
    for (int j = 0; j < 16; ++j) {
        if ((eqcA >> j) & 1u) {
            unsigned i1 = idx_of(sA[j], C1A, B1A);
            if (i1 > d1A) abvA |= (1u << j);
            else if (i1 == d1A) tieA |= (1u << j);
        }
        if ((eqcB >> j) & 1u) {
            unsigned i1 = idx_of(sB[j], C1B, B1B);
            if (i1 > d1B) abvB |= (1u << j);
            else if (i1 == d1B) tieB |= (1u << j);
        }
    }

    // Phase 3: softmax + PV via mask bits; exp2 (scores pre-scaled by log2e)
    float dA = 0.f, dB = 0.f;
    float4 A = {0.f, 0.f, 0.f, 0.f}, Bv = {0.f, 0.f, 0.f, 0.f};
    #pragma unroll
    for (int j = 0; j < 16; ++j) {
        float4 vv = vb4[tid + (j << 8)];
        {
            float w = __builtin_amdgcn_exp2f(sA[j] - MXA);
            w = ((abvA >> j) & 1u) ? w : (((tieA >> j) & 1u) ? w * seA : 0.f);
            dA += w;
            A.x = fmaf(w, vv.x, A.x); A.y = fmaf(w, vv.y, A.y);
            A.z = fmaf(w, vv.z, A.z); A.w = fmaf(w, vv.w, A.w);
        }
        {
            float w = __builtin_amdgcn_exp2f(sB[j] - MXB);
            w = ((abvB >> j) & 1u) ? w : (((tieB >> j) & 1u) ? w * seB : 0.f);
            dB += w;
            Bv.x = fmaf(w, vv.x, Bv.x); Bv.y = fmaf(w, vv.y, Bv.y);
            Bv.z = fmaf(w, vv.z, Bv.z); Bv.w = fmaf(w, vv.w, Bv.w);
        }
    }
    #pragma unroll
    for (int off = 32; off > 0; off >>= 1) {
        dA += __shfl_down(dA, off, 64);
        A.x += __shfl_down(A.x, off, 64); A.y += __shfl_down(A.y, off, 64);
        A.z += __shfl_down(A.z, off, 64); A.w += __shfl_down(A.w, off, 64);
        dB += __shfl_down(dB, off, 64);
        Bv.x += __shfl_down(Bv.x, off, 64); Bv.y += __shfl_down(Bv.y, off, 64);
        Bv.z += __shfl_down(Bv.z, off, 64); Bv.w += __shfl_down(Bv.w, off, 64);
    }
    if (lane == 0) {
        float* r = red[wv];
        r[0] = dA; r[1] = A.x; r[2] = A.y; r[3] = A.z; r[4] = A.w;
        r[5] = dB; r[6] = Bv.x; r[7] = Bv.y; r[8] = Bv.z; r[9] = Bv.w;
    }
    __syncthreads();                               // B6
    if (tid < 2) {
        int base = tid * 5;
        float D  = red[0][base] + red[1][base] + red[2][base] + red[3][base];
        float o0 = red[0][base + 1] + red[1][base + 1] + red[2][base + 1] + red[3][base + 1];
        float o1 = red[0][base + 2] + red[1][base + 2] + red[2][base + 2] + red[3][base + 2];
        float o2 = red[0][base + 3] + red[1][base + 3] + red[2][base + 3] + red[3][base + 3];
        float o3 = red[0][base + 4] + red[1][base + 4] + red[2][base + 4] + red[3][base + 4];
        float invD = 1.f / D;
        int n = n0 + tid;
        outp[((head << 2) + 0) * NTOK + n] = o0 * invD;
        outp[((head << 2) + 1) * NTOK + n] = o1 * invD;
        outp[((head << 2) + 2) * NTOK + n] = o2 * invD;
        outp[((head << 2) + 3) * NTOK + n] = o3 * invD;
    }
}

// out[o][p] = sum_ch wp[o][ch] * ao[head(ch)*4+cph(ch)][p*4 + t(ch)], ch = t*32 + head*4 + cph
__global__ void k_proj(const float* __restrict__ ao, const float* __restrict__ wp,
                       float* __restrict__ out) {
    __shared__ float chin[128];
    int p = blockIdx.x;
    int tid = threadIdx.x;       // 128
    int t = tid >> 5;
    int c = tid & 31;
    chin[tid] = ao[c * NTOK + (p << 2) + t];
    __syncthreads();
    const float* wr = wp + tid * 128;
    float acc = 0.f;
    #pragma unroll 8
    for (int ch = 0; ch < 128; ++ch) acc = fmaf(wr[ch], chin[ch], acc);
    out[tid * 1024 + p] = acc;
}

extern "C" void kernel_launch(void* const* d_in, const int* in_sizes, int n_in,
                              void* d_out, int out_size, void* d_ws, size_t ws_size,
                              hipStream_t stream) {
    const float* x    = (const float*)d_in[0];
    const float* temp = (const float*)d_in[1];
    const float* wq   = (const float*)d_in[2];
    const float* wdw  = (const float*)d_in[3];
    const float* wp   = (const float*)d_in[4];
    float* out = (float*)d_out;
    float* ws = (float*)d_ws;

    float* qh = ws;                      // [head][n][4] = 131072 floats
    float* kh = qh + 131072;
    float* vh = kh + 131072;
    float* ao = vh + 131072;             // [c][n]
    float* ssb = ao + 131072;            // 64 floats

    hipMemsetAsync(ssb, 0, 64 * sizeof(float), stream);
    k_fused<<<384,   256, 0, stream>>>(x, wq, wdw, qh, kh, vh, ssb);
    k_attn <<<16384, 256, 0, stream>>>(qh, kh, vh, ssb, temp, ao);
    k_proj <<<1024,  128, 0, stream>>>(ao, wp, out);
}